// Round 2
// baseline (336.974 us; speedup 1.0000x reference)
//
#include <hip/hip_runtime.h>

// StockLSTM R15: register-neutral 2-blocks/CU (fixes R14's spill regression).
//  Keep R13's wave structure exactly (16 waves, ONE 16x16 tile per wave,
//  A-frags = 28 VGPRs, ~56 total) but MT=8, grid=512 -> 2 independent
//  barrier domains per CU at 32 waves/CU (100% occupancy).
//  Column-dup via ADDRESSING: B-fragments read with b8=lane&7, so lanes
//  b8 and b8+8 broadcast-read the same LDS (no dup stores, no conflicts).
//  Cols 0-7 and 8-15 of every MFMA carry the same 8 batches; lane
//  sel=(lane>>3)&1 then owns ONE cell: sel=0 -> layer-1 cell from a1,
//  sel=1 -> layer-2 cell from a2 (its column is a valid dup). Per lane:
//  1 cell_update (half of R13's transcendental work), 1 ds_write_b16 to a
//  precomputed parity pointer, 4 cndmask. Numerics identical to R13.
//  Cost: MFMA/CU-step doubles (224, ~45% util) -- pipe had headroom.
//  Watchdog: VGPR must stay <=64 (waves_per_eu(8,8)); spill signature is
//  WRITE_SIZE >> 0.4 MB.

#define TT   256
#define II   5
#define HH   64
#define OO   25
#define MT   8
#define NTHR 1024
#define XP   520        // x chunk row stride (ushorts): 64*8 + 8 skew
#define HSZ  512        // h parity block: 64 k * 8 batch shorts
#define HF   65

typedef __attribute__((ext_vector_type(8))) short  short8;
typedef __attribute__((ext_vector_type(4))) float  floatx4;

#define MFMA(a, b, c) __builtin_amdgcn_mfma_f32_16x16x32_bf16(a, b, c, 0, 0, 0)

__device__ __forceinline__ float frcp(float x) { return __builtin_amdgcn_rcpf(x); }
__device__ __forceinline__ float fexp2(float x) { return __builtin_amdgcn_exp2f(x); }
__device__ __forceinline__ unsigned short bf16_rne(float f) {
    unsigned int u = __builtin_bit_cast(unsigned int, f);
    u += 0x7FFFu + ((u >> 16) & 1u);
    return (unsigned short)(u >> 16);
}
// gates arrive PRE-SCALED: g0,g1,g3 = -log2e*z ; g2 = +2log2e*z
__device__ __forceinline__ float cell_update(const floatx4& g, float& c) {
    const float gi = frcp(1.f + fexp2(g[0]));
    const float gf = frcp(1.f + fexp2(g[1]));
    const float gz = fmaf(-2.f, frcp(1.f + fexp2(g[2])), 1.f);
    const float go = frcp(1.f + fexp2(g[3]));
    c = fmaf(gf, c, gi * gz);
    const float tc = fmaf(-2.f, frcp(1.f + fexp2(c * 2.885390082f)), 1.f);
    return go * tc;
}

__global__ __attribute__((amdgpu_flat_work_group_size(1024, 1024),
                          amdgpu_waves_per_eu(8, 8)))
void lstm_mfma11(const float* __restrict__ x,
                 const float* __restrict__ Wih0, const float* __restrict__ Whh0,
                 const float* __restrict__ bih0, const float* __restrict__ bhh0,
                 const float* __restrict__ Wih1, const float* __restrict__ Whh1,
                 const float* __restrict__ bih1, const float* __restrict__ bhh1,
                 const float* __restrict__ Wfc,  const float* __restrict__ bfc,
                 float* __restrict__ out)
{
    __shared__ __align__(16) unsigned short xhi[MT * XP];     // 8.3 KB
    __shared__ __align__(16) unsigned short h1hi[2 * HSZ];    // 2 KB
    __shared__ __align__(16) unsigned short h2hi[2 * HSZ];    // 2 KB
    __shared__ __align__(16) float          h2f[MT * HF];

    const int tid   = threadIdx.x;
    const int w     = tid >> 6;          // wave 0..15
    const int lane  = tid & 63;
    const int b8    = lane & 7;          // batch col (8 real; cols 8-15 dup)
    const int q     = lane >> 4;         // k-slice / C row-quad
    const int sel   = (lane >> 3) & 1;   // 0: own L1 cell, 1: own L2 cell
    const bool isl2 = (sel != 0);
    const int jmine = 4 * w + q;
    const int hw_base = ((jmine >> 3) * 8 + b8) * 8 + (jmine & 7);  // shorts
    const int ro8     = (q * 8 + b8) * 8;  // B-frag read offset (broadcast pairs)

    // ---------------- weights (bf16), nonlinearity scale folded in ----------------
    // EXACTLY R13's single-tile-per-wave fragments (register-neutral).
    short8 A1h[2];   // Whh0 k-chunks
    short8 A2h[4];   // 0,1: Wih1 (h1 side); 2,3: Whh1 (h2 side)
    short8 Axwh;     // Wih0: k<II valid, rest exact zero
    {
        const int rr = lane & 15;
        const int g  = (rr & 3) * 64 + 4 * w + (rr >> 2);
        const float sc = ((rr & 3) == 2) ? 2.885390082f : -1.442695041f;
        #pragma unroll
        for (int c = 0; c < 2; ++c)
            #pragma unroll
            for (int jj = 0; jj < 8; ++jj)
                A1h[c][jj] = (short)bf16_rne(sc * Whh0[g * HH + c * 32 + q * 8 + jj]);
        #pragma unroll
        for (int c = 0; c < 4; ++c)
            #pragma unroll
            for (int jj = 0; jj < 8; ++jj) {
                const int k = c * 32 + q * 8 + jj;
                float wv = (k < HH) ? Wih1[g * HH + k] : Whh1[g * HH + (k - HH)];
                A2h[c][jj] = (short)bf16_rne(sc * wv);
            }
        #pragma unroll
        for (int jj = 0; jj < 8; ++jj) {
            const int k = q * 8 + jj;
            Axwh[jj] = (k < II) ? (short)bf16_rne(sc * Wih0[g * II + k]) : (short)0;
        }
    }
    // bias as MFMA C-operand (row-dependent only -> valid for dup columns)
    floatx4 bias1v, bias2v;
    #pragma unroll
    for (int r = 0; r < 4; ++r) {
        const int g = r * 64 + jmine;
        const float sc = (r == 2) ? 2.885390082f : -1.442695041f;
        bias1v[r] = sc * (bih0[g] + bhh0[g]);
        bias2v[r] = sc * (bih1[g] + bhh1[g]);
    }

    // ---------------- zero LDS ----------------
    for (int i = tid; i < MT * XP / 2; i += NTHR)
        ((unsigned int*)xhi)[i] = 0u;
    if (tid < HSZ) {
        ((unsigned int*)h1hi)[tid] = 0u;
        ((unsigned int*)h2hi)[tid] = 0u;
    }
    float c1 = 0.f;                       // ONE cell state per lane
    __syncthreads();

    const int blockBase = blockIdx.x * MT;

    auto refill_x = [&](int t0) {
        if (tid < 512) {
            const int rb = tid >> 6, dt = tid & 63;   // rows 0..7
            const float* src = x + ((size_t)(blockBase + rb) * TT + t0 + dt) * II;
            unsigned short* ph = xhi + rb * XP + dt * 8;
            #pragma unroll
            for (int ii = 0; ii < II; ++ii)
                ph[ii] = bf16_rne(src[ii]);
        }
    };

    // ================= prologue: L1(0) =================
    refill_x(0);
    __syncthreads();
    {
        short8 Bxh = *(const short8*)(xhi + b8 * XP);       // dt = 0
        floatx4 a1 = MFMA(Axwh, Bxh, bias1v);
        if (!isl2) {
            const float h = cell_update(a1, c1);
            h1hi[hw_base] = bf16_rne(h);                    // parity 0
        }
    }
    __syncthreads();

    // per-lane write pointers: even intervals write h2->parity0 / h1->parity1,
    // odd intervals the opposite. Chosen once; zero per-step address math.
    unsigned short* const wptrE = isl2 ? (h2hi + hw_base) : (h1hi + HSZ + hw_base);
    unsigned short* const wptrO = isl2 ? (h2hi + HSZ + hw_base) : (h1hi + hw_base);

    // x read pointer: STEP(i) reads dt=(i+1)&63; starts at dt=1.
    const unsigned short* xptr = xhi + b8 * XP + 8;

    // ================= merged main loop, unrolled by 2 =================
#define STEP_BODY(WP, RP, WPTR)                                               \
    {                                                                         \
        short8 H1h0 = *(const short8*)(h1hi + (WP) * HSZ + ro8);              \
        short8 H1h1 = *(const short8*)(h1hi + (WP) * HSZ + 256 + ro8);        \
        short8 H2h0 = *(const short8*)(h2hi + (RP) * HSZ + ro8);              \
        short8 H2h1 = *(const short8*)(h2hi + (RP) * HSZ + 256 + ro8);        \
        short8 Bxh  = *(const short8*)(xptr);                                 \
        xptr += 8;                                                            \
        floatx4 a2 = MFMA(A2h[0], H1h0, bias2v);                              \
        a2 = MFMA(A2h[1], H1h1, a2);                                          \
        a2 = MFMA(A2h[2], H2h0, a2);                                          \
        a2 = MFMA(A2h[3], H2h1, a2);                                          \
        floatx4 a1 = MFMA(Axwh, Bxh, bias1v);                                 \
        a1 = MFMA(A1h[0], H1h0, a1);                                          \
        a1 = MFMA(A1h[1], H1h1, a1);                                          \
        floatx4 g;                                                            \
        _Pragma("unroll")                                                     \
        for (int r = 0; r < 4; ++r) g[r] = isl2 ? a2[r] : a1[r];              \
        const float h = cell_update(g, c1);                                   \
        *(WPTR) = bf16_rne(h);                                                \
        __syncthreads();                                                      \
    }

    for (int i = 0; i < 254; i += 2) {
        STEP_BODY(0, 1, wptrE)               // interval i   (even)
        if (((i + 2) & 63) == 0) {           // refill before interval i+1
            refill_x(i + 2);
            xptr = xhi + b8 * XP;            //   next read is dt = 0
            __syncthreads();
        }
        STEP_BODY(1, 0, wptrO)               // interval i+1 (odd)
    }
    STEP_BODY(0, 1, wptrE)                   // interval 254
#undef STEP_BODY

    // ================= epilogue: L2(255) =================
    {
        short8 H1h0 = *(const short8*)(h1hi + 1 * HSZ + ro8);
        short8 H1h1 = *(const short8*)(h1hi + 1 * HSZ + 256 + ro8);
        short8 H2h0 = *(const short8*)(h2hi + 0 * HSZ + ro8);
        short8 H2h1 = *(const short8*)(h2hi + 0 * HSZ + 256 + ro8);
        floatx4 a2 = MFMA(A2h[0], H1h0, bias2v);
        a2 = MFMA(A2h[1], H1h1, a2);
        a2 = MFMA(A2h[2], H2h0, a2);
        a2 = MFMA(A2h[3], H2h1, a2);
        if (isl2) {
            const float h = cell_update(a2, c1);
            h2f[b8 * HF + jmine] = h;
        }
    }
    __syncthreads();

    // ================= FC epilogue =================
    if (tid < MT * OO) {
        const int bb = tid / OO, o = tid - bb * OO;
        float acc = bfc[o];
        const float* wr = Wfc + o * HH;
        const float* hr = h2f + bb * HF;
        #pragma unroll
        for (int j = 0; j < HH; ++j) acc += wr[j] * hr[j];
        out[((size_t)blockIdx.x * MT + bb) * OO + o] = acc;
    }
}

extern "C" void kernel_launch(void* const* d_in, const int* in_sizes, int n_in,
                              void* d_out, int out_size, void* d_ws, size_t ws_size,
                              hipStream_t stream) {
    const float* x    = (const float*)d_in[0];
    const float* Wih0 = (const float*)d_in[1];
    const float* Whh0 = (const float*)d_in[2];
    const float* bih0 = (const float*)d_in[3];
    const float* bhh0 = (const float*)d_in[4];
    const float* Wih1 = (const float*)d_in[5];
    const float* Whh1 = (const float*)d_in[6];
    const float* bih1 = (const float*)d_in[7];
    const float* bhh1 = (const float*)d_in[8];
    const float* Wfc  = (const float*)d_in[9];
    const float* bfc  = (const float*)d_in[10];
    float* out = (float*)d_out;

    dim3 grid(4096 / MT), block(NTHR);
    lstm_mfma11<<<grid, block, 0, stream>>>(x, Wih0, Whh0, bih0, bhh0,
                                            Wih1, Whh1, bih1, bhh1,
                                            Wfc, bfc, out);
}

// Round 3
// 264.332 us; speedup vs baseline: 1.2748x; 1.2748x over previous
//
#include <hip/hip_runtime.h>

// StockLSTM R16 = R13 + wave-parity phase skew (+ setprio on MFMA clusters).
//  R14/R15 post-mortem: 2 blocks/CU is unreachable -- the ~70-reg live set
//  spills at the 64-reg budget that 8 waves/SIMD requires (R15: 76 MB scratch
//  writes). Abandoned. Instead attack the real serialization: R13's counters
//  (VALU 62% + MFMA 24% ~= 86% summed) show the pipes run back-to-back, not
//  overlapped, because all 4 waves/SIMD hit the MFMA burst and the
//  transcendental cell phase in lockstep. R16 skews wave parity:
//   even-parity waves: [a2 4-MFMA; a1 3-MFMA; cell2; cell1]   (R13 order)
//   odd-parity waves:  [a1 3-MFMA; cell1; a2 4-MFMA; cell2]
//  so each SIMD always has one parity in MFMA while the other is in VALU.
//  sched_barrier(0) pins the odd arm's VALU phase between its MFMA bursts;
//  setprio(1) around MFMA clusters (T5 regime: wave role diversity now
//  exists). Registers/LDS/barrier structure byte-identical to R13 (56 VGPR,
//  1 block/CU, grid=256).

#define TT   256
#define II   5
#define HH   64
#define OO   25
#define MT   16
#define NTHR 1024
#define XP   520        // x chunk row stride (ushorts): 64*8 + 8 skew
#define HSZ  1024       // h parity block: 64 k * 16 batch shorts
#define HF   65

typedef __attribute__((ext_vector_type(8))) short  short8;
typedef __attribute__((ext_vector_type(4))) float  floatx4;

#define MFMA(a, b, c) __builtin_amdgcn_mfma_f32_16x16x32_bf16(a, b, c, 0, 0, 0)

__device__ __forceinline__ float frcp(float x) { return __builtin_amdgcn_rcpf(x); }
__device__ __forceinline__ float fexp2(float x) { return __builtin_amdgcn_exp2f(x); }
__device__ __forceinline__ unsigned short bf16_rne(float f) {
    unsigned int u = __builtin_bit_cast(unsigned int, f);
    u += 0x7FFFu + ((u >> 16) & 1u);
    return (unsigned short)(u >> 16);
}
// gates arrive PRE-SCALED: g0,g1,g3 = -log2e*z ; g2 = +2log2e*z
__device__ __forceinline__ float cell_update(const floatx4& g, float& c) {
    const float gi = frcp(1.f + fexp2(g[0]));
    const float gf = frcp(1.f + fexp2(g[1]));
    const float gz = fmaf(-2.f, frcp(1.f + fexp2(g[2])), 1.f);
    const float go = frcp(1.f + fexp2(g[3]));
    c = fmaf(gf, c, gi * gz);
    const float tc = fmaf(-2.f, frcp(1.f + fexp2(c * 2.885390082f)), 1.f);
    return go * tc;
}

__global__ __attribute__((amdgpu_flat_work_group_size(1024, 1024),
                          amdgpu_waves_per_eu(4, 4)))
void lstm_mfma12(const float* __restrict__ x,
                 const float* __restrict__ Wih0, const float* __restrict__ Whh0,
                 const float* __restrict__ bih0, const float* __restrict__ bhh0,
                 const float* __restrict__ Wih1, const float* __restrict__ Whh1,
                 const float* __restrict__ bih1, const float* __restrict__ bhh1,
                 const float* __restrict__ Wfc,  const float* __restrict__ bfc,
                 float* __restrict__ out)
{
    __shared__ __align__(16) unsigned short xhi[MT * XP];     // 16.6 KB
    __shared__ __align__(16) unsigned short h1hi[2 * HSZ];    // 4 KB each
    __shared__ __align__(16) unsigned short h2hi[2 * HSZ];
    __shared__ __align__(16) float          h2f[MT * HF];

    const int tid   = threadIdx.x;
    const int w     = tid >> 6;
    const int lane  = tid & 63;
    const int b     = lane & 15;      // batch col
    const int q     = lane >> 4;      // k-slice / C row-quad
    const int jmine = 4 * w + q;
    const int hw_off = ((jmine >> 3) * 16 + b) * 8 + (jmine & 7);
    const int ro     = lane * 8;      // fragment read offset: lane*16B
    // phase-skew parity: balanced for both w%4 and w/4 wave->SIMD mappings
    const bool pE = (((w ^ (w >> 2)) & 1) == 0);

    // ---------------- weights (bf16), nonlinearity scale folded in ----------------
    short8 A1h[2];   // Whh0 k-chunks
    short8 A2h[4];   // 0,1: Wih1 (h1 side); 2,3: Whh1 (h2 side)
    short8 Axwh;     // Wih0: k<II valid, rest exact zero
    {
        const int rr = lane & 15;
        const int g  = (rr & 3) * 64 + 4 * w + (rr >> 2);
        const float sc = ((rr & 3) == 2) ? 2.885390082f : -1.442695041f;
        #pragma unroll
        for (int c = 0; c < 2; ++c)
            #pragma unroll
            for (int jj = 0; jj < 8; ++jj)
                A1h[c][jj] = (short)bf16_rne(sc * Whh0[g * HH + c * 32 + q * 8 + jj]);
        #pragma unroll
        for (int c = 0; c < 4; ++c)
            #pragma unroll
            for (int jj = 0; jj < 8; ++jj) {
                const int k = c * 32 + q * 8 + jj;
                float wv = (k < HH) ? Wih1[g * HH + k] : Whh1[g * HH + (k - HH)];
                A2h[c][jj] = (short)bf16_rne(sc * wv);
            }
        #pragma unroll
        for (int jj = 0; jj < 8; ++jj) {
            const int k = q * 8 + jj;
            Axwh[jj] = (k < II) ? (short)bf16_rne(sc * Wih0[g * II + k]) : (short)0;
        }
    }
    float bias1[4], bias2[4];
    #pragma unroll
    for (int r = 0; r < 4; ++r) {
        const int g = r * 64 + jmine;
        const float sc = (r == 2) ? 2.885390082f : -1.442695041f;
        bias1[r] = sc * (bih0[g] + bhh0[g]);
        bias2[r] = sc * (bih1[g] + bhh1[g]);
    }

    // ---------------- zero LDS ----------------
    for (int i = tid; i < MT * XP / 2; i += NTHR)
        ((unsigned int*)xhi)[i] = 0u;
    for (int i = tid; i < HSZ; i += NTHR) {
        ((unsigned int*)h1hi)[i] = 0u;
        ((unsigned int*)h2hi)[i] = 0u;
    }
    float c1 = 0.f, c2 = 0.f;
    __syncthreads();

    const int blockBase = blockIdx.x * MT;

    auto refill_x = [&](int t0) {
        const int rb = tid >> 6, dt = tid & 63;
        const float* src = x + ((size_t)(blockBase + rb) * TT + t0 + dt) * II;
        unsigned short* ph = xhi + rb * XP + dt * 8;
        #pragma unroll
        for (int ii = 0; ii < II; ++ii)
            ph[ii] = bf16_rne(src[ii]);
    };

    // ================= prologue: L1(0) =================
    refill_x(0);
    __syncthreads();
    {
        short8 Bxh = *(const short8*)(xhi + b * XP);       // dt = 0
        floatx4 a1 = {bias1[0], bias1[1], bias1[2], bias1[3]};
        a1 = MFMA(Axwh, Bxh, a1);
        const float h = cell_update(a1, c1);
        h1hi[0 * HSZ + hw_off] = bf16_rne(h);              // parity 0
    }
    __syncthreads();

    // x read pointer: STEP(i) reads dt=(i+1)&63; starts at dt=1.
    const unsigned short* xptr = xhi + b * XP + 8;

    // ================= merged main loop, unrolled by 2 =================
    // STEP(WP,RP): compile-time parity -> all h LDS accesses reg+imm.
    // pE waves: MFMA-burst then VALU-burst; !pE waves: MFMA/VALU alternated.
#define STEP_BODY(WP, RP)                                                     \
    {                                                                         \
        short8 H1h0 = *(const short8*)(h1hi + (WP) * HSZ + ro);               \
        short8 H1h1 = *(const short8*)(h1hi + (WP) * HSZ + 512 + ro);         \
        short8 H2h0 = *(const short8*)(h2hi + (RP) * HSZ + ro);               \
        short8 H2h1 = *(const short8*)(h2hi + (RP) * HSZ + 512 + ro);         \
        short8 Bxh  = *(const short8*)(xptr);                                 \
        xptr += 8;                                                            \
        if (pE) {                                                             \
            __builtin_amdgcn_s_setprio(1);                                    \
            floatx4 a2 = {bias2[0], bias2[1], bias2[2], bias2[3]};            \
            a2 = MFMA(A2h[0], H1h0, a2);                                      \
            a2 = MFMA(A2h[1], H1h1, a2);                                      \
            a2 = MFMA(A2h[2], H2h0, a2);                                      \
            a2 = MFMA(A2h[3], H2h1, a2);                                      \
            floatx4 a1 = {bias1[0], bias1[1], bias1[2], bias1[3]};            \
            a1 = MFMA(Axwh, Bxh, a1);                                         \
            a1 = MFMA(A1h[0], H1h0, a1);                                      \
            a1 = MFMA(A1h[1], H1h1, a1);                                      \
            __builtin_amdgcn_s_setprio(0);                                    \
            {                                                                 \
                const float h = cell_update(a2, c2);                          \
                h2hi[(WP) * HSZ + hw_off] = bf16_rne(h);                      \
            }                                                                 \
            {                                                                 \
                const float h = cell_update(a1, c1);                          \
                h1hi[(RP) * HSZ + hw_off] = bf16_rne(h);                      \
            }                                                                 \
        } else {                                                              \
            __builtin_amdgcn_s_setprio(1);                                    \
            floatx4 a1 = {bias1[0], bias1[1], bias1[2], bias1[3]};            \
            a1 = MFMA(Axwh, Bxh, a1);                                         \
            a1 = MFMA(A1h[0], H1h0, a1);                                      \
            a1 = MFMA(A1h[1], H1h1, a1);                                      \
            __builtin_amdgcn_s_setprio(0);                                    \
            {                                                                 \
                const float h = cell_update(a1, c1);                          \
                h1hi[(RP) * HSZ + hw_off] = bf16_rne(h);                      \
            }                                                                 \
            __builtin_amdgcn_sched_barrier(0);  /* keep cell1 here */         \
            __builtin_amdgcn_s_setprio(1);                                    \
            floatx4 a2 = {bias2[0], bias2[1], bias2[2], bias2[3]};            \
            a2 = MFMA(A2h[0], H1h0, a2);                                      \
            a2 = MFMA(A2h[1], H1h1, a2);                                      \
            a2 = MFMA(A2h[2], H2h0, a2);                                      \
            a2 = MFMA(A2h[3], H2h1, a2);                                      \
            __builtin_amdgcn_s_setprio(0);                                    \
            {                                                                 \
                const float h = cell_update(a2, c2);                          \
                h2hi[(WP) * HSZ + hw_off] = bf16_rne(h);                      \
            }                                                                 \
        }                                                                     \
        __syncthreads();                                                      \
    }

    for (int i = 0; i < 254; i += 2) {
        STEP_BODY(0, 1)                      // interval i   (even)
        if (((i + 2) & 63) == 0) {           // refill before interval i+1
            refill_x(i + 2);                 //   when (i+2) % 64 == 0
            xptr = xhi + b * XP;             //   next read is dt = 0
            __syncthreads();
        }
        STEP_BODY(1, 0)                      // interval i+1 (odd)
    }
    STEP_BODY(0, 1)                          // interval 254
#undef STEP_BODY

    // ================= epilogue: L2(255) =================
    {
        short8 H1h0 = *(const short8*)(h1hi + 1 * HSZ + ro);
        short8 H1h1 = *(const short8*)(h1hi + 1 * HSZ + 512 + ro);
        short8 H2h0 = *(const short8*)(h2hi + 0 * HSZ + ro);
        short8 H2h1 = *(const short8*)(h2hi + 0 * HSZ + 512 + ro);
        floatx4 a2 = {bias2[0], bias2[1], bias2[2], bias2[3]};
        a2 = MFMA(A2h[0], H1h0, a2);
        a2 = MFMA(A2h[1], H1h1, a2);
        a2 = MFMA(A2h[2], H2h0, a2);
        a2 = MFMA(A2h[3], H2h1, a2);
        const float h = cell_update(a2, c2);
        h2f[b * HF + jmine] = h;
    }
    __syncthreads();

    // ================= FC epilogue =================
    if (tid < MT * OO) {
        const int bb = tid / OO, o = tid - bb * OO;
        float acc = bfc[o];
        const float* wr = Wfc + o * HH;
        const float* hr = h2f + bb * HF;
        #pragma unroll
        for (int j = 0; j < HH; ++j) acc += wr[j] * hr[j];
        out[((size_t)blockIdx.x * MT + bb) * OO + o] = acc;
    }
}

extern "C" void kernel_launch(void* const* d_in, const int* in_sizes, int n_in,
                              void* d_out, int out_size, void* d_ws, size_t ws_size,
                              hipStream_t stream) {
    const float* x    = (const float*)d_in[0];
    const float* Wih0 = (const float*)d_in[1];
    const float* Whh0 = (const float*)d_in[2];
    const float* bih0 = (const float*)d_in[3];
    const float* bhh0 = (const float*)d_in[4];
    const float* Wih1 = (const float*)d_in[5];
    const float* Whh1 = (const float*)d_in[6];
    const float* bih1 = (const float*)d_in[7];
    const float* bhh1 = (const float*)d_in[8];
    const float* Wfc  = (const float*)d_in[9];
    const float* bfc  = (const float*)d_in[10];
    float* out = (float*)d_out;

    dim3 grid(4096 / MT), block(NTHR);
    lstm_mfma12<<<grid, block, 0, stream>>>(x, Wih0, Whh0, bih0, bhh0,
                                            Wih1, Whh1, bih1, bhh1,
                                            Wfc, bfc, out);
}